// Round 1
// baseline (472.502 us; speedup 1.0000x reference)
//
#include <hip/hip_runtime.h>

// Problem constants (from reference):
//   VOC_SIZE = 1,000,000, EMBED_DIM = 64, N_UPD = 262,144, B*L = 819,200
// Inputs (order from setup_inputs):
//   d_in[0]: kernel      float32 [1,000,000 * 64]
//   d_in[1]: indices     int     [262,144]
//   d_in[2]: emb_update  float32 [262,144 * 64]
//   d_in[3]: qs          int     [819,200]
// Output: float32 [819,200 * 64]

#define EMBED_DIM 64

// One thread per update element: 64 threads cooperate on one update row.
// Consecutive threads touch consecutive floats of the same table row ->
// coalesced atomicAdd traffic. Scatter goes directly into d_in[0]; the
// harness restores inputs from pristine copies before every timed launch.
__global__ void scatter_add_kernel(float* __restrict__ table,
                                   const int* __restrict__ indices,
                                   const float* __restrict__ upd,
                                   int total /* n_upd * 64 */) {
    int tid = blockIdx.x * blockDim.x + threadIdx.x;
    if (tid >= total) return;
    int i = tid >> 6;   // update row
    int d = tid & 63;   // column
    int row = indices[i];
    atomicAdd(&table[(size_t)row * EMBED_DIM + d], upd[tid]);
}

// One thread per output float4: 16 threads cooperate on one 256 B row.
// Reads are 16 B/lane contiguous within each row; writes fully coalesced.
__global__ void gather_kernel(const float4* __restrict__ table,
                              const int* __restrict__ qs,
                              float4* __restrict__ out,
                              int total /* n_q * 16 */) {
    int tid = blockIdx.x * blockDim.x + threadIdx.x;
    if (tid >= total) return;
    int r = tid >> 4;   // query index
    int c = tid & 15;   // float4 chunk within the row
    int q = qs[r];
    out[tid] = table[q * 16 + c];
}

extern "C" void kernel_launch(void* const* d_in, const int* in_sizes, int n_in,
                              void* d_out, int out_size, void* d_ws, size_t ws_size,
                              hipStream_t stream) {
    float* table = (float*)d_in[0];                    // mutated in place
    const int* indices = (const int*)d_in[1];
    const float* upd = (const float*)d_in[2];
    const int* qs = (const int*)d_in[3];
    float* out = (float*)d_out;

    const int n_upd = in_sizes[1];                     // 262,144
    const int n_q = in_sizes[3];                       // 819,200

    const int scatter_total = n_upd * EMBED_DIM;       // 16,777,216
    const int gather_total = n_q * (EMBED_DIM / 4);    // 13,107,200

    const int block = 256;
    scatter_add_kernel<<<(scatter_total + block - 1) / block, block, 0, stream>>>(
        table, indices, upd, scatter_total);
    gather_kernel<<<(gather_total + block - 1) / block, block, 0, stream>>>(
        (const float4*)table, qs, (float4*)out, gather_total);
}